// Round 4
// baseline (1786.012 us; speedup 1.0000x reference)
//
#include <hip/hip_runtime.h>
#include <hip/hip_bf16.h>
#include <math.h>

typedef __hip_bfloat16 bf16;

#define BATCH 2
#define SEQ   2048
#define DM    1024
#define NH    16
#define HD    64
#define MTOT  (BATCH*SEQ)            // 4096
#define SZO   ((size_t)MTOT * DM)    // 4,194,304 elements

// ---------------------------------------------------------------------------
// Kernel A: K/V projections (x @ W^T), RoPE fused for K. fp32 in, bf16 out.
// K -> ws (8 MiB). V -> upper half of d_out (bf16 view, 8 MiB).
// 64x64 C-tile, 256 threads, 4x4 microtile, K-step 16.
// grid = (MTOT/64, NH, 2)  z: 0=K(+RoPE), 1=V.
// ---------------------------------------------------------------------------
__global__ __launch_bounds__(256) void kv_rope_kernel(
    const float* __restrict__ x, const float* __restrict__ Wk,
    const float* __restrict__ Wv, bf16* __restrict__ K, bf16* __restrict__ V)
{
    const int zz = blockIdx.z;
    const float* __restrict__ W    = (zz == 0) ? Wk : Wv;
    bf16*        __restrict__ outp = (zz == 0) ? K  : V;

    const int m0 = blockIdx.x * 64;
    const int h  = blockIdx.y;
    const int e0 = h * 64;
    const int tid = threadIdx.x;
    const int tx = tid & 15, ty = tid >> 4;

    __shared__ float As[16][65];   // [k][m]
    __shared__ float Bs[16][65];   // [k][e]
    __shared__ float Cs[64][65];   // C tile for RoPE epilogue

    float acc[4][4] = {};

    for (int k0 = 0; k0 < DM; k0 += 16) {
        #pragma unroll
        for (int l = 0; l < 4; ++l) {
            int idx = tid + l * 256;
            int mm = idx >> 4, kk = idx & 15;
            As[kk][mm] = x[(size_t)(m0 + mm) * DM + k0 + kk];
            Bs[kk][mm] = W[(size_t)(e0 + mm) * DM + k0 + kk];
        }
        __syncthreads();
        #pragma unroll
        for (int kk = 0; kk < 16; ++kk) {
            float a[4], b[4];
            #pragma unroll
            for (int i = 0; i < 4; ++i) a[i] = As[kk][ty * 4 + i];
            #pragma unroll
            for (int j = 0; j < 4; ++j) b[j] = Bs[kk][tx * 4 + j];
            #pragma unroll
            for (int i = 0; i < 4; ++i)
                #pragma unroll
                for (int j = 0; j < 4; ++j)
                    acc[i][j] += a[i] * b[j];
        }
        __syncthreads();
    }

    #pragma unroll
    for (int i = 0; i < 4; ++i)
        #pragma unroll
        for (int j = 0; j < 4; ++j)
            Cs[ty * 4 + i][tx * 4 + j] = acc[i][j];
    __syncthreads();

    const float LN1E4_D32 = 0.28782313662425572f;   // ln(10000)/32
    for (int idx = tid; idx < 64 * 64; idx += 256) {
        int mm = idx >> 6, j = idx & 63;
        int m = m0 + mm;
        int bb = m >> 11;            // m / SEQ
        int n  = m & (SEQ - 1);
        float v = Cs[mm][j];
        float res;
        if (zz == 0) {               // RoPE on K only
            int jj = j & 31;
            float inv_freq = expf(-(float)jj * LN1E4_D32);
            float ang = (float)n * inv_freq;
            float c, s;
            sincosf(ang, &s, &c);
            float rot = (j < 32) ? -Cs[mm][j + 32] : Cs[mm][j - 32];
            res = v * c + rot * s;
        } else {
            res = v;
        }
        outp[((size_t)(bb * NH + h) * SEQ + n) * HD + j] = __float2bfloat16(res);
    }
}

// ---------------------------------------------------------------------------
// Kernel B: fused per-(q-tile, head): Q-proj (64x64 GEMM, fp32 in) + RoPE +
// flash attention (online softmax) over bf16 K/V chunks of 64 keys.
// O-tile (bf16) -> lower half of d_out (block-exclusive; scratch).
// grid = (MTOT/64, NH), 256 threads.
// ---------------------------------------------------------------------------
__global__ __launch_bounds__(256) void fused_attn_kernel(
    const float* __restrict__ x, const float* __restrict__ Wq,
    const bf16* __restrict__ Kg, const bf16* __restrict__ Vg,
    const int* __restrict__ mask, bf16* __restrict__ Ob)
{
    const int m0 = blockIdx.x * 64;
    const int h  = blockIdx.y;
    const int b  = m0 >> 11;
    const int n0 = m0 & (SEQ - 1);
    const int bh = b * NH + h;
    const bf16* __restrict__ Kh = Kg + (size_t)bh * SEQ * HD;
    const bf16* __restrict__ Vh = Vg + (size_t)bh * SEQ * HD;
    const int tid = threadIdx.x;
    const int tx = tid & 15, ty = tid >> 4;

    __shared__ float As[16][65];
    __shared__ float Bs[16][65];
    __shared__ float Qs[64][65];    // RoPE'd, pre-scaled Q tile
    __shared__ float Ks[64][65];    // K chunk
    __shared__ float Vs[64][65];    // V chunk
    __shared__ float Ss[64][65];    // scores -> probabilities (also RoPE stage)
    __shared__ float mrow[64], lrow[64], arow[64];

    // ---- Phase 1: Qh = x_tile @ Wq_h^T (fp32 acc) ----
    float acc[4][4] = {};
    for (int k0 = 0; k0 < DM; k0 += 16) {
        #pragma unroll
        for (int l = 0; l < 4; ++l) {
            int idx = tid + l * 256;
            int mm = idx >> 4, kk = idx & 15;
            As[kk][mm] = x[(size_t)(m0 + mm) * DM + k0 + kk];
            Bs[kk][mm] = Wq[(size_t)(h * 64 + mm) * DM + k0 + kk];
        }
        __syncthreads();
        #pragma unroll
        for (int kk = 0; kk < 16; ++kk) {
            float a[4], bb2[4];
            #pragma unroll
            for (int i = 0; i < 4; ++i) a[i] = As[kk][ty * 4 + i];
            #pragma unroll
            for (int j = 0; j < 4; ++j) bb2[j] = Bs[kk][tx * 4 + j];
            #pragma unroll
            for (int i = 0; i < 4; ++i)
                #pragma unroll
                for (int j = 0; j < 4; ++j)
                    acc[i][j] += a[i] * bb2[j];
        }
        __syncthreads();
    }
    #pragma unroll
    for (int i = 0; i < 4; ++i)
        #pragma unroll
        for (int j = 0; j < 4; ++j)
            Ss[ty * 4 + i][tx * 4 + j] = acc[i][j];   // stage for RoPE
    __syncthreads();

    // ---- RoPE + fold in softmax scale (1/8); init online-softmax state ----
    const float LN1E4_D32 = 0.28782313662425572f;
    for (int idx = tid; idx < 64 * 64; idx += 256) {
        int mm = idx >> 6, j = idx & 63;
        int n = n0 + mm;
        int jj = j & 31;
        float inv_freq = expf(-(float)jj * LN1E4_D32);
        float ang = (float)n * inv_freq;
        float c, s;
        sincosf(ang, &s, &c);
        float v = Ss[mm][j];
        float rot = (j < 32) ? -Ss[mm][j + 32] : Ss[mm][j - 32];
        Qs[mm][j] = 0.125f * (v * c + rot * s);
    }
    if (tid < 64) { mrow[tid] = -INFINITY; lrow[tid] = 0.f; }
    __syncthreads();

    // ---- Phase 2: flash loop over 64-key chunks ----
    float o[4][4] = {};
    for (int c0 = 0; c0 < SEQ; c0 += 64) {
        for (int idx = tid; idx < 64 * 64; idx += 256) {
            int kk = idx >> 6, d = idx & 63;
            Ks[kk][d] = __bfloat162float(Kh[(size_t)(c0 + kk) * HD + d]);
            Vs[kk][d] = __bfloat162float(Vh[(size_t)(c0 + kk) * HD + d]);
        }
        __syncthreads();

        // S = Qs @ Ks^T (scale pre-folded), masked
        float sreg[4][4] = {};
        #pragma unroll 8
        for (int d = 0; d < 64; ++d) {
            float qv[4], kv[4];
            #pragma unroll
            for (int i = 0; i < 4; ++i) qv[i] = Qs[ty * 4 + i][d];
            #pragma unroll
            for (int j = 0; j < 4; ++j) kv[j] = Ks[tx * 4 + j][d];
            #pragma unroll
            for (int i = 0; i < 4; ++i)
                #pragma unroll
                for (int j = 0; j < 4; ++j)
                    sreg[i][j] += qv[i] * kv[j];
        }
        #pragma unroll
        for (int i = 0; i < 4; ++i)
            #pragma unroll
            for (int j = 0; j < 4; ++j) {
                int key = c0 + tx * 4 + j;
                Ss[ty * 4 + i][tx * 4 + j] =
                    mask[b * SEQ + key] ? sreg[i][j] : -INFINITY;
            }
        __syncthreads();

        // online-softmax row pass (one thread per q-row)
        if (tid < 64) {
            int q = tid;
            float mold = mrow[q], mnew = mold;
            #pragma unroll 8
            for (int k = 0; k < 64; ++k) mnew = fmaxf(mnew, Ss[q][k]);
            float alpha = (mnew == -INFINITY) ? 1.f : __expf(mold - mnew);
            float ls = 0.f;
            #pragma unroll 8
            for (int k = 0; k < 64; ++k) {
                float sv = Ss[q][k];
                float p = (sv == -INFINITY) ? 0.f : __expf(sv - mnew);
                Ss[q][k] = p;
                ls += p;
            }
            lrow[q] = lrow[q] * alpha + ls;
            mrow[q] = mnew;
            arow[q] = alpha;
        }
        __syncthreads();

        // O = O*alpha + P @ V_chunk
        #pragma unroll
        for (int i = 0; i < 4; ++i) {
            float a = arow[ty * 4 + i];
            #pragma unroll
            for (int j = 0; j < 4; ++j) o[i][j] *= a;
        }
        #pragma unroll 8
        for (int k = 0; k < 64; ++k) {
            float pv[4], vv[4];
            #pragma unroll
            for (int i = 0; i < 4; ++i) pv[i] = Ss[ty * 4 + i][k];
            #pragma unroll
            for (int j = 0; j < 4; ++j) vv[j] = Vs[k][tx * 4 + j];
            #pragma unroll
            for (int i = 0; i < 4; ++i)
                #pragma unroll
                for (int j = 0; j < 4; ++j)
                    o[i][j] += pv[i] * vv[j];
        }
        __syncthreads();
    }

    // ---- finalize: divide by l, store bf16 O-tile (block-exclusive) ----
    #pragma unroll
    for (int i = 0; i < 4; ++i) {
        int q = ty * 4 + i;
        float inv = (lrow[q] > 0.f) ? 1.f / lrow[q] : 0.f;
        #pragma unroll
        for (int j = 0; j < 4; ++j)
            Ob[(size_t)(m0 + q) * DM + h * HD + tx * 4 + j] =
                __float2bfloat16(o[i][j] * inv);
    }
}

// ---------------------------------------------------------------------------
// Kernel C: out = O @ Wo^T (O bf16 in ws), fp32 store to d_out.
// grid = (MTOT/64, DM/64)
// ---------------------------------------------------------------------------
__global__ __launch_bounds__(256) void oproj_kernel(
    const bf16* __restrict__ Oin, const float* __restrict__ Wo,
    float* __restrict__ out)
{
    const int m0 = blockIdx.x * 64;
    const int e0 = blockIdx.y * 64;
    const int tid = threadIdx.x;
    const int tx = tid & 15, ty = tid >> 4;

    __shared__ float As[16][65];
    __shared__ float Bs[16][65];

    float acc[4][4] = {};
    for (int k0 = 0; k0 < DM; k0 += 16) {
        #pragma unroll
        for (int l = 0; l < 4; ++l) {
            int idx = tid + l * 256;
            int mm = idx >> 4, kk = idx & 15;
            As[kk][mm] = __bfloat162float(Oin[(size_t)(m0 + mm) * DM + k0 + kk]);
            Bs[kk][mm] = Wo[(size_t)(e0 + mm) * DM + k0 + kk];
        }
        __syncthreads();
        #pragma unroll
        for (int kk = 0; kk < 16; ++kk) {
            float a[4], bb2[4];
            #pragma unroll
            for (int i = 0; i < 4; ++i) a[i] = As[kk][ty * 4 + i];
            #pragma unroll
            for (int j = 0; j < 4; ++j) bb2[j] = Bs[kk][tx * 4 + j];
            #pragma unroll
            for (int i = 0; i < 4; ++i)
                #pragma unroll
                for (int j = 0; j < 4; ++j)
                    acc[i][j] += a[i] * bb2[j];
        }
        __syncthreads();
    }

    #pragma unroll
    for (int i = 0; i < 4; ++i) {
        int m = m0 + ty * 4 + i;
        #pragma unroll
        for (int j = 0; j < 4; ++j) {
            int e = e0 + tx * 4 + j;
            out[(size_t)m * DM + e] = acc[i][j];
        }
    }
}

// ---------------------------------------------------------------------------
extern "C" void kernel_launch(void* const* d_in, const int* in_sizes, int n_in,
                              void* d_out, int out_size, void* d_ws, size_t ws_size,
                              hipStream_t stream)
{
    const float* x    = (const float*)d_in[0];
    const int*   mask = (const int*)d_in[1];
    const float* Wq   = (const float*)d_in[2];
    const float* Wk   = (const float*)d_in[3];
    const float* Wv   = (const float*)d_in[4];
    const float* Wo   = (const float*)d_in[5];
    float* out = (float*)d_out;

    // Scratch plan (peak d_ws use: 8 MiB):
    //   ws[0 .. 8MiB)        : K bf16  (kernel A) -> later O bf16 copy
    //   d_out bf16-view:
    //     [0 .. SZO)         : O bf16  (kernel B scratch, lower half)
    //     [SZO .. 2*SZO)     : V bf16  (kernel A, upper half)
    bf16* K  = (bf16*)d_ws;
    bf16* Ob = (bf16*)d_out;
    bf16* V  = (bf16*)d_out + SZO;

    dim3 gA(MTOT / 64, NH, 2);
    kv_rope_kernel<<<gA, 256, 0, stream>>>(x, Wk, Wv, K, V);

    dim3 gB(MTOT / 64, NH);
    fused_attn_kernel<<<gB, 256, 0, stream>>>(x, Wq, K, V, mask, Ob);

    // Move O (lower half of d_out) into ws (K region is dead) so kernel C can
    // overwrite all of d_out without read/write overlap across blocks.
    hipMemcpyAsync(d_ws, d_out, SZO * sizeof(bf16),
                   hipMemcpyDeviceToDevice, stream);

    dim3 gC(MTOT / 64, DM / 64);
    oproj_kernel<<<gC, 256, 0, stream>>>((const bf16*)d_ws, Wo, out);
}

// Round 5
// 385.369 us; speedup vs baseline: 4.6346x; 4.6346x over previous
//
#include <hip/hip_runtime.h>
#include <math.h>

#define BATCH 2
#define SEQ   2048
#define DM    1024
#define NH    16
#define HD    64
#define MTOT  (BATCH*SEQ)            // 4096

typedef short v8s __attribute__((ext_vector_type(8)));
typedef float v4f __attribute__((ext_vector_type(4)));

#define MFMA16(a, b, c) __builtin_amdgcn_mfma_f32_16x16x32_bf16((a), (b), (c), 0, 0, 0)

__device__ __forceinline__ short f2b(float f) {          // fp32 -> bf16 bits, RNE
    union { float f; unsigned u; } v; v.f = f;
    unsigned r = (v.u + 0x7FFFu + ((v.u >> 16) & 1u)) >> 16;
    return (short)r;
}

// ---------------------------------------------------------------------------
// Kernel 0: fp32 -> bf16-bits elementwise convert (8 elems / thread).
// ---------------------------------------------------------------------------
__global__ __launch_bounds__(256) void cvt_kernel(
    const float* __restrict__ src, short* __restrict__ dst, int n8)
{
    int i = blockIdx.x * 256 + threadIdx.x;
    if (i >= n8) return;
    const float4* s4 = (const float4*)src;
    float4 a = s4[2 * i], b = s4[2 * i + 1];
    v8s p;
    p[0] = f2b(a.x); p[1] = f2b(a.y); p[2] = f2b(a.z); p[3] = f2b(a.w);
    p[4] = f2b(b.x); p[5] = f2b(b.y); p[6] = f2b(b.z); p[7] = f2b(b.w);
    *(v8s*)&dst[8 * i] = p;
}

// ---------------------------------------------------------------------------
// Kernel 1: K/V projections via MFMA. z=0: K = RoPE(x @ Wk^T) -> [bh][key][d]
//           z=1: V = x @ Wv^T stored TRANSPOSED -> Vt[bh][d][key]
// 64x64 C-tile, 256 thr / 4 waves, wave w owns m-strip [16w,16w+16), 4 n-tiles.
// grid = (MTOT/64, NH, 2)
// ---------------------------------------------------------------------------
__global__ __launch_bounds__(256) void kv_rope_mfma(
    const short* __restrict__ xb, const short* __restrict__ Wkb,
    const short* __restrict__ Wvb, short* __restrict__ K, short* __restrict__ Vt)
{
    const int zz = blockIdx.z;
    const short* __restrict__ Wb = zz ? Wvb : Wkb;
    const int m0 = blockIdx.x * 64, h = blockIdx.y, e0 = h * 64;
    const int tid = threadIdx.x;
    const int w = tid >> 6, lane = tid & 63, lq = lane >> 4, lr = lane & 15;
    const int sr = tid >> 2, sc = (tid & 3) * 8;

    __shared__ short As[64][32];
    __shared__ short Bs[64][32];
    __shared__ float Cs[64][65];

    v4f acc[4];
    #pragma unroll
    for (int nt = 0; nt < 4; ++nt)
        for (int r = 0; r < 4; ++r) acc[nt][r] = 0.f;

    for (int k0 = 0; k0 < DM; k0 += 32) {
        v8s av = *(const v8s*)&xb[(size_t)(m0 + sr) * DM + k0 + sc];
        v8s bv = *(const v8s*)&Wb[(size_t)(e0 + sr) * DM + k0 + sc];
        __syncthreads();
        *(v8s*)&As[sr][sc] = av;
        *(v8s*)&Bs[sr][sc] = bv;
        __syncthreads();
        v8s a = *(const v8s*)&As[16 * w + lr][lq * 8];
        #pragma unroll
        for (int nt = 0; nt < 4; ++nt) {
            v8s b = *(const v8s*)&Bs[16 * nt + lr][lq * 8];
            acc[nt] = MFMA16(a, b, acc[nt]);
        }
    }

    #pragma unroll
    for (int nt = 0; nt < 4; ++nt)
        #pragma unroll
        for (int r = 0; r < 4; ++r)
            Cs[16 * w + lq * 4 + r][16 * nt + lr] = acc[nt][r];
    __syncthreads();

    const int b = m0 >> 11, n0 = m0 & (SEQ - 1);
    const int bh = b * NH + h;
    const float LN1E4_D32 = 0.28782313662425572f;   // ln(10000)/32

    if (zz == 0) {
        // RoPE, then coalesced K store: thread -> (row mm, 16 cols)
        int mm = tid >> 2, d0 = (tid & 3) * 16;
        int n = n0 + mm;
        v8s o1, o2;
        #pragma unroll
        for (int i = 0; i < 16; ++i) {
            int j = d0 + i, jj = j & 31;
            float inv_freq = expf(-(float)jj * LN1E4_D32);
            float ang = (float)n * inv_freq;
            float c, s;
            sincosf(ang, &s, &c);
            float v = Cs[mm][j];
            float rot = (j < 32) ? -Cs[mm][j + 32] : Cs[mm][j - 32];
            short bb = f2b(v * c + rot * s);
            if (i < 8) o1[i] = bb; else o2[i - 8] = bb;
        }
        size_t base = ((size_t)bh * SEQ + n) * HD + d0;
        *(v8s*)&K[base] = o1;
        *(v8s*)&K[base + 8] = o2;
    } else {
        // transpose store: thread -> (dim d, 16 keys)
        int d = tid >> 2, ks0 = (tid & 3) * 16;
        v8s o1, o2;
        #pragma unroll
        for (int i = 0; i < 8; ++i) {
            o1[i] = f2b(Cs[ks0 + i][d]);
            o2[i] = f2b(Cs[ks0 + 8 + i][d]);
        }
        size_t base = ((size_t)bh * HD + d) * SEQ + n0 + ks0;
        *(v8s*)&Vt[base] = o1;
        *(v8s*)&Vt[base + 8] = o2;
    }
}

// ---------------------------------------------------------------------------
// Kernel 2: fused Q-proj (MFMA) + RoPE + flash attention (MFMA QK^T and PV,
// register-resident online softmax, P via LDS round-trip). O -> ws (bf16).
// grid = (MTOT/64, NH), 256 threads / 4 waves.
// ---------------------------------------------------------------------------
__global__ __launch_bounds__(256) void attn_mfma(
    const short* __restrict__ xb, const short* __restrict__ Wqb,
    const short* __restrict__ K, const short* __restrict__ Vt,
    const int* __restrict__ mask, short* __restrict__ O)
{
    const int m0 = blockIdx.x * 64, h = blockIdx.y, e0 = h * 64;
    const int b = m0 >> 11, n0 = m0 & (SEQ - 1), bh = b * NH + h;
    const int tid = threadIdx.x;
    const int w = tid >> 6, lane = tid & 63, lq = lane >> 4, lr = lane & 15;
    const int sr = tid >> 2, sc = (tid & 3) * 8;

    __shared__ union SA {
        struct { short As[64][32]; short Bs[64][32]; } p1;  // phase 1
        short Ps[64][72];                                    // phase 2
    } sa;
    __shared__ union SB {
        float Cs[64][65];                                    // RoPE staging
        struct { short Ks[64][72]; short Vs[64][72]; } p2;   // phase 2
    } sb;
    __shared__ short Qs[64][72];
    __shared__ int mbuf[64];

    // ---- Phase 1: Q-tile = x_tile @ Wq_h^T ----
    v4f acc[4];
    #pragma unroll
    for (int nt = 0; nt < 4; ++nt)
        for (int r = 0; r < 4; ++r) acc[nt][r] = 0.f;

    for (int k0 = 0; k0 < DM; k0 += 32) {
        v8s av = *(const v8s*)&xb[(size_t)(m0 + sr) * DM + k0 + sc];
        v8s bv = *(const v8s*)&Wqb[(size_t)(e0 + sr) * DM + k0 + sc];
        __syncthreads();
        *(v8s*)&sa.p1.As[sr][sc] = av;
        *(v8s*)&sa.p1.Bs[sr][sc] = bv;
        __syncthreads();
        v8s a = *(const v8s*)&sa.p1.As[16 * w + lr][lq * 8];
        #pragma unroll
        for (int nt = 0; nt < 4; ++nt) {
            v8s bb = *(const v8s*)&sa.p1.Bs[16 * nt + lr][lq * 8];
            acc[nt] = MFMA16(a, bb, acc[nt]);
        }
    }
    #pragma unroll
    for (int nt = 0; nt < 4; ++nt)
        #pragma unroll
        for (int r = 0; r < 4; ++r)
            sb.Cs[16 * w + lq * 4 + r][16 * nt + lr] = acc[nt][r];
    __syncthreads();

    // ---- RoPE + fold softmax scale (1/8) -> Qs bf16 ----
    {
        const float LN1E4_D32 = 0.28782313662425572f;
        int mm = tid >> 2, d0 = (tid & 3) * 16;
        int n = n0 + mm;
        #pragma unroll
        for (int i = 0; i < 16; ++i) {
            int j = d0 + i, jj = j & 31;
            float inv_freq = expf(-(float)jj * LN1E4_D32);
            float ang = (float)n * inv_freq;
            float c, s;
            sincosf(ang, &s, &c);
            float v = sb.Cs[mm][j];
            float rot = (j < 32) ? -sb.Cs[mm][j + 32] : sb.Cs[mm][j - 32];
            Qs[mm][j] = f2b(0.125f * (v * c + rot * s));
        }
    }

    // ---- Phase 2: flash loop, 64-key chunks ----
    float mrun[4], lrun[4];
    #pragma unroll
    for (int r = 0; r < 4; ++r) { mrun[r] = -INFINITY; lrun[r] = 0.f; }
    v4f o[4];
    #pragma unroll
    for (int nt = 0; nt < 4; ++nt)
        for (int r = 0; r < 4; ++r) o[nt][r] = 0.f;

    for (int c0 = 0; c0 < SEQ; c0 += 64) {
        __syncthreads();   // prior chunk's Ks/Vs reads (and Cs/Qs phase) done
        {
            int r2 = tid >> 2, cc = (tid & 3) * 16;
            v8s k1 = *(const v8s*)&K[((size_t)bh * SEQ + c0 + r2) * HD + cc];
            v8s k2 = *(const v8s*)&K[((size_t)bh * SEQ + c0 + r2) * HD + cc + 8];
            v8s v1 = *(const v8s*)&Vt[((size_t)bh * HD + r2) * SEQ + c0 + cc];
            v8s v2 = *(const v8s*)&Vt[((size_t)bh * HD + r2) * SEQ + c0 + cc + 8];
            *(v8s*)&sb.p2.Ks[r2][cc] = k1;
            *(v8s*)&sb.p2.Ks[r2][cc + 8] = k2;
            *(v8s*)&sb.p2.Vs[r2][cc] = v1;
            *(v8s*)&sb.p2.Vs[r2][cc + 8] = v2;
            if (tid < 64) mbuf[tid] = mask[b * SEQ + c0 + tid];
        }
        __syncthreads();

        // S = Q @ K^T  (scale pre-folded into Q)
        v4f s[4];
        #pragma unroll
        for (int nt = 0; nt < 4; ++nt)
            for (int r = 0; r < 4; ++r) s[nt][r] = 0.f;
        #pragma unroll
        for (int ks = 0; ks < 2; ++ks) {
            v8s a = *(const v8s*)&Qs[16 * w + lr][ks * 32 + lq * 8];
            #pragma unroll
            for (int nt = 0; nt < 4; ++nt) {
                v8s bb = *(const v8s*)&sb.p2.Ks[16 * nt + lr][ks * 32 + lq * 8];
                s[nt] = MFMA16(a, bb, s[nt]);
            }
        }
        // mask (key = c0 + 16*nt + lr; all 4 rows in a reg share the col)
        #pragma unroll
        for (int nt = 0; nt < 4; ++nt) {
            if (!mbuf[16 * nt + lr]) {
                s[nt][0] = -INFINITY; s[nt][1] = -INFINITY;
                s[nt][2] = -INFINITY; s[nt][3] = -INFINITY;
            }
        }
        // online softmax, all in registers (butterfly over the 16-lane col group)
        float alpha[4];
        #pragma unroll
        for (int r = 0; r < 4; ++r) {
            float mc = fmaxf(fmaxf(s[0][r], s[1][r]), fmaxf(s[2][r], s[3][r]));
            mc = fmaxf(mc, __shfl_xor(mc, 1));
            mc = fmaxf(mc, __shfl_xor(mc, 2));
            mc = fmaxf(mc, __shfl_xor(mc, 4));
            mc = fmaxf(mc, __shfl_xor(mc, 8));
            float mnew = fmaxf(mrun[r], mc);
            alpha[r] = (mnew == -INFINITY) ? 1.f : __expf(mrun[r] - mnew);
            mrun[r] = mnew;
        }
        float rs[4] = {0.f, 0.f, 0.f, 0.f};
        #pragma unroll
        for (int nt = 0; nt < 4; ++nt) {
            #pragma unroll
            for (int r = 0; r < 4; ++r) {
                float sv = s[nt][r];
                float p = (sv == -INFINITY) ? 0.f : __expf(sv - mrun[r]);
                rs[r] += p;
                sa.Ps[16 * w + lq * 4 + r][16 * nt + lr] = f2b(p);
            }
        }
        #pragma unroll
        for (int r = 0; r < 4; ++r) {
            rs[r] += __shfl_xor(rs[r], 1);
            rs[r] += __shfl_xor(rs[r], 2);
            rs[r] += __shfl_xor(rs[r], 4);
            rs[r] += __shfl_xor(rs[r], 8);
            lrun[r] = lrun[r] * alpha[r] + rs[r];
        }
        #pragma unroll
        for (int nt = 0; nt < 4; ++nt)
            #pragma unroll
            for (int r = 0; r < 4; ++r) o[nt][r] *= alpha[r];

        // O += P @ V   (Ps rows are wave-private: no barrier needed)
        #pragma unroll
        for (int ks = 0; ks < 2; ++ks) {
            v8s a = *(const v8s*)&sa.Ps[16 * w + lr][ks * 32 + lq * 8];
            #pragma unroll
            for (int nt = 0; nt < 4; ++nt) {
                v8s bb = *(const v8s*)&sb.p2.Vs[16 * nt + lr][ks * 32 + lq * 8];
                o[nt] = MFMA16(a, bb, o[nt]);
            }
        }
    }

    // ---- finalize ----
    #pragma unroll
    for (int r = 0; r < 4; ++r) {
        float inv = (lrun[r] > 0.f) ? 1.f / lrun[r] : 0.f;
        int qrow = 16 * w + lq * 4 + r;
        #pragma unroll
        for (int nt = 0; nt < 4; ++nt)
            O[(size_t)(m0 + qrow) * DM + h * HD + 16 * nt + lr] =
                f2b(o[nt][r] * inv);
    }
}

// ---------------------------------------------------------------------------
// Kernel 3: out = O @ Wo^T via MFMA, fp32 store. grid = (MTOT/64, DM/64).
// ---------------------------------------------------------------------------
__global__ __launch_bounds__(256) void oproj_mfma(
    const short* __restrict__ O, const short* __restrict__ Wob,
    float* __restrict__ out)
{
    const int m0 = blockIdx.x * 64, e0 = blockIdx.y * 64;
    const int tid = threadIdx.x;
    const int w = tid >> 6, lane = tid & 63, lq = lane >> 4, lr = lane & 15;
    const int sr = tid >> 2, sc = (tid & 3) * 8;

    __shared__ short As[64][32];
    __shared__ short Bs[64][32];

    v4f acc[4];
    #pragma unroll
    for (int nt = 0; nt < 4; ++nt)
        for (int r = 0; r < 4; ++r) acc[nt][r] = 0.f;

    for (int k0 = 0; k0 < DM; k0 += 32) {
        v8s av = *(const v8s*)&O[(size_t)(m0 + sr) * DM + k0 + sc];
        v8s bv = *(const v8s*)&Wob[(size_t)(e0 + sr) * DM + k0 + sc];
        __syncthreads();
        *(v8s*)&As[sr][sc] = av;
        *(v8s*)&Bs[sr][sc] = bv;
        __syncthreads();
        v8s a = *(const v8s*)&As[16 * w + lr][lq * 8];
        #pragma unroll
        for (int nt = 0; nt < 4; ++nt) {
            v8s bb = *(const v8s*)&Bs[16 * nt + lr][lq * 8];
            acc[nt] = MFMA16(a, bb, acc[nt]);
        }
    }

    #pragma unroll
    for (int r = 0; r < 4; ++r) {
        int m = m0 + 16 * w + lq * 4 + r;
        #pragma unroll
        for (int nt = 0; nt < 4; ++nt)
            out[(size_t)m * DM + e0 + 16 * nt + lr] = acc[nt][r];
    }
}

// ---------------------------------------------------------------------------
extern "C" void kernel_launch(void* const* d_in, const int* in_sizes, int n_in,
                              void* d_out, int out_size, void* d_ws, size_t ws_size,
                              hipStream_t stream)
{
    const float* x    = (const float*)d_in[0];
    const int*   mask = (const int*)d_in[1];
    const float* Wq   = (const float*)d_in[2];
    const float* Wk   = (const float*)d_in[3];
    const float* Wv   = (const float*)d_in[4];
    const float* Wo   = (const float*)d_in[5];
    float* out = (float*)d_out;

    // ws (24 MiB of shorts): xb | Wqb | Wkb | Wvb | Wob | O
    short* xb  = (short*)d_ws;                    // 4 Mi
    short* Wqb = xb  + (size_t)MTOT * DM;         // 1 Mi
    short* Wkb = Wqb + (size_t)DM * DM;
    short* Wvb = Wkb + (size_t)DM * DM;
    short* Wob = Wvb + (size_t)DM * DM;
    short* O   = Wob + (size_t)DM * DM;           // 4 Mi
    // d_out (16 MiB) doubles as K/Vt scratch until the final projection
    short* K  = (short*)d_out;                    // 4 Mi
    short* Vt = K + (size_t)MTOT * DM;            // 4 Mi

    const int NX8 = MTOT * DM / 8, NW8 = DM * DM / 8;
    cvt_kernel<<<(NX8 + 255) / 256, 256, 0, stream>>>(x, xb, NX8);
    cvt_kernel<<<(NW8 + 255) / 256, 256, 0, stream>>>(Wq, Wqb, NW8);
    cvt_kernel<<<(NW8 + 255) / 256, 256, 0, stream>>>(Wk, Wkb, NW8);
    cvt_kernel<<<(NW8 + 255) / 256, 256, 0, stream>>>(Wv, Wvb, NW8);
    cvt_kernel<<<(NW8 + 255) / 256, 256, 0, stream>>>(Wo, Wob, NW8);

    dim3 g1(MTOT / 64, NH, 2);
    kv_rope_mfma<<<g1, 256, 0, stream>>>(xb, Wkb, Wvb, K, Vt);

    dim3 g2(MTOT / 64, NH);
    attn_mfma<<<g2, 256, 0, stream>>>(xb, Wqb, K, Vt, mask, O);

    dim3 g3(MTOT / 64, DM / 64);
    oproj_mfma<<<g3, 256, 0, stream>>>(O, Wob, out);
}